// Round 1
// baseline (4480.995 us; speedup 1.0000x reference)
//
#include <hip/hip_runtime.h>
#include <math.h>

// Problem constants (Swin-ish LocalContext block)
#define B_   64
#define C_   256
#define L_   1600          // H*W = 40*40
#define NH   8
#define HD   32
#define T_   25            // tokens per window (5x5)
#define NWIN 64            // windows per image (8x8)
#define D2   512
#define HID  1024
#define ROWS (B_*L_)       // 102400
#define QSCALE 0.17677669529663687f   // 1/sqrt(32)

// ---------------------------------------------------------------------------
// LN1 stats: per (b,l) row over C=256 channels of x (B,C,L)
__global__ __launch_bounds__(256) void ln1_stats(const float* __restrict__ x,
                                                 float* __restrict__ mu,
                                                 float* __restrict__ rs) {
  int r = blockIdx.x * 256 + threadIdx.x;   // global row
  int b = r / L_;
  int l = r - b * L_;
  const float* xp = x + (size_t)b * (C_ * L_) + l;
  float s = 0.f, s2 = 0.f;
#pragma unroll 8
  for (int c = 0; c < C_; ++c) {
    float v = xp[(size_t)c * L_];
    s += v; s2 += v * v;
  }
  float m = s * (1.0f / C_);
  float var = s2 * (1.0f / C_) - m * m;
  mu[r] = m;
  rs[r] = rsqrtf(var + 1e-5f);
}

// ---------------------------------------------------------------------------
// QKV GEMM: out(ROWS,768) = LN1(x^T)(ROWS,256) @ qkv_w(256,768) + qkv_b
// x is (B,C,L): A^T layout -> coalesced k-slice loads along rows.
__global__ __launch_bounds__(256) void qkv_gemm(const float* __restrict__ x,
    const float* __restrict__ mu, const float* __restrict__ rs,
    const float* __restrict__ g, const float* __restrict__ be,
    const float* __restrict__ w, const float* __restrict__ wb,
    float* __restrict__ outp) {
  __shared__ float As[16][128];
  __shared__ float Bs[16][128];
  __shared__ float gL[C_], beL[C_], muL[128], rsL[128];
  int tid = threadIdx.x;
  int r0 = blockIdx.x * 128;
  int n0 = blockIdx.y * 128;
  gL[tid] = g[tid]; beL[tid] = be[tid];
  if (tid < 128) { muL[tid] = mu[r0 + tid]; rsL[tid] = rs[r0 + tid]; }
  __syncthreads();

  float acc[8][8] = {};
  int tx = tid & 15, ty = tid >> 4;

  for (int k0 = 0; k0 < C_; k0 += 16) {
#pragma unroll
    for (int i = 0; i < 8; ++i) {
      int e = tid + i * 256;
      int m = e & 127, kk = e >> 7;
      int gr = r0 + m;
      int bb = gr / L_;
      int kg = k0 + kk;
      // x[b][kg][l] with l = gr - b*L :  b*C*L + kg*L + gr - b*L
      float v = x[(size_t)bb * (C_ * L_ - L_) + (size_t)kg * L_ + gr];
      As[kk][m] = (v - muL[m]) * rsL[m] * gL[kg] + beL[kg];
    }
#pragma unroll
    for (int i = 0; i < 8; ++i) {
      int e = tid + i * 256;
      int j = e & 127, kk = e >> 7;
      Bs[kk][j] = w[(size_t)(k0 + kk) * 768 + n0 + j];
    }
    __syncthreads();
#pragma unroll
    for (int kk = 0; kk < 16; ++kk) {
      float a[8], bv[8];
      *(float4*)&a[0]  = *(const float4*)&As[kk][ty * 8];
      *(float4*)&a[4]  = *(const float4*)&As[kk][ty * 8 + 4];
      *(float4*)&bv[0] = *(const float4*)&Bs[kk][tx * 8];
      *(float4*)&bv[4] = *(const float4*)&Bs[kk][tx * 8 + 4];
#pragma unroll
      for (int i2 = 0; i2 < 8; ++i2)
#pragma unroll
        for (int j2 = 0; j2 < 8; ++j2)
          acc[i2][j2] += a[i2] * bv[j2];
    }
    __syncthreads();
  }

  float4 wb0 = *(const float4*)&wb[n0 + tx * 8];
  float4 wb1 = *(const float4*)&wb[n0 + tx * 8 + 4];
#pragma unroll
  for (int i = 0; i < 8; ++i) {
    int row = r0 + ty * 8 + i;
    float4 o0 = make_float4(acc[i][0] + wb0.x, acc[i][1] + wb0.y,
                            acc[i][2] + wb0.z, acc[i][3] + wb0.w);
    float4 o1 = make_float4(acc[i][4] + wb1.x, acc[i][5] + wb1.y,
                            acc[i][6] + wb1.z, acc[i][7] + wb1.w);
    float4* p = (float4*)&outp[(size_t)row * 768 + n0 + tx * 8];
    p[0] = o0; p[1] = o1;
  }
}

// ---------------------------------------------------------------------------
// Window attention: one block per (b, window). qkv cols are which*256 + d*8 + h;
// we stage LDS permuted to which*256 + h*32 + d for contiguous per-head access.
__global__ __launch_bounds__(256) void attn_kernel(const float* __restrict__ qkv,
                                                   const float* __restrict__ rel,
                                                   float* __restrict__ outp) {
  __shared__ float qk[T_][776];       // padded row stride (bank spread)
  __shared__ float sL[NH * T_ * T_];  // 5000 scores
  int tid = threadIdx.x;
  int bn = blockIdx.x;
  int b = bn >> 6, n = bn & 63;
  int u = n >> 3, v = n & 7;

  // stage 25 rows x 768 (coalesced global reads, permuted LDS writes)
  for (int e = tid; e < T_ * 768; e += 256) {
    int t = e / 768;
    int col = e - t * 768;
    int which = col >> 8;
    int cm = col & 255;
    int d = cm >> 3, h = cm & 7;
    int i = t / 5, j = t - i * 5;
    int l = (u * 5 + i) * 40 + v * 5 + j;
    float val = qkv[(size_t)(b * L_ + l) * 768 + col];
    if (which == 0) val *= QSCALE;
    qk[t][which * 256 + h * 32 + d] = val;
  }
  __syncthreads();

  // scores S[h][t][s] = q.k + bias + mask
  for (int e = tid; e < NH * T_ * T_; e += 256) {
    int h = e / 625;
    int r = e - h * 625;
    int t = r / 25, s = r - t * 25;
    const float* qp = &qk[t][h * 32];
    const float* kp = &qk[s][256 + h * 32];
    float dot = 0.f;
#pragma unroll
    for (int d = 0; d < 32; d += 4) {
      float4 q4 = *(const float4*)(qp + d);
      float4 k4 = *(const float4*)(kp + d);
      dot += q4.x * k4.x + q4.y * k4.y + q4.z * k4.z + q4.w * k4.w;
    }
    int i1 = t / 5, j1 = t - i1 * 5;
    int i2 = s / 5, j2 = s - i2 * 5;
    int ridx = (i1 - i2 + 4) * 9 + (j1 - j2 + 4);
    float bias = rel[ridx * 8 + h];
    int p1 = ((u * 5 + i1) + (v * 5 + j1)) & 1;
    int p2 = ((u * 5 + i2) + (v * 5 + j2)) & 1;
    float mval = (p1 & p2) ? 0.0f : -100.0f;
    sL[e] = dot + bias + mval;
  }
  __syncthreads();

  // softmax over s for 200 (h,t) rows
  if (tid < NH * T_) {
    float* row = &sL[tid * 25];
    float mx = row[0];
#pragma unroll
    for (int s = 1; s < 25; ++s) mx = fmaxf(mx, row[s]);
    float sum = 0.f;
#pragma unroll
    for (int s = 0; s < 25; ++s) { float p = __expf(row[s] - mx); row[s] = p; sum += p; }
    float inv = 1.0f / sum;
#pragma unroll
    for (int s = 0; s < 25; ++s) row[s] *= inv;
  }
  __syncthreads();

  // out[t][h*32+d] = sum_s p * v ; write channel order c = h*32+d
  for (int e = tid; e < T_ * 64; e += 256) {
    int t = e >> 6;
    int cq = e & 63;
    int h = cq >> 3;
    int dq = (cq & 7) * 4;
    const float* pr = &sL[(h * 25 + t) * 25];
    float4 acc = make_float4(0.f, 0.f, 0.f, 0.f);
#pragma unroll
    for (int s = 0; s < 25; ++s) {
      float p = pr[s];
      const float4 v4 = *(const float4*)&qk[s][512 + h * 32 + dq];
      acc.x += p * v4.x; acc.y += p * v4.y; acc.z += p * v4.z; acc.w += p * v4.w;
    }
    int i = t / 5, j = t - i * 5;
    int l = (u * 5 + i) * 40 + v * 5 + j;
    *(float4*)&outp[(size_t)(b * L_ + l) * 256 + h * 32 + dq] = acc;
  }
}

// ---------------------------------------------------------------------------
// proj GEMM: y(ROWS,512) = attn_out(ROWS,256) @ proj_w(256,512) + proj_b
__global__ __launch_bounds__(256) void proj_gemm(const float* __restrict__ a,
    const float* __restrict__ w, const float* __restrict__ wb,
    float* __restrict__ outp) {
  __shared__ float As[16][128];
  __shared__ float Bs[16][128];
  int tid = threadIdx.x;
  int r0 = blockIdx.x * 128;
  int n0 = blockIdx.y * 128;
  float acc[8][8] = {};
  int tx = tid & 15, ty = tid >> 4;

  for (int k0 = 0; k0 < C_; k0 += 16) {
#pragma unroll
    for (int i = 0; i < 2; ++i) {
      int e = tid + i * 256;
      int m = e >> 2, qd = e & 3;
      float4 vv = *(const float4*)&a[(size_t)(r0 + m) * 256 + k0 + qd * 4];
      As[qd * 4 + 0][m] = vv.x; As[qd * 4 + 1][m] = vv.y;
      As[qd * 4 + 2][m] = vv.z; As[qd * 4 + 3][m] = vv.w;
    }
#pragma unroll
    for (int i = 0; i < 8; ++i) {
      int e = tid + i * 256;
      int j = e & 127, kk = e >> 7;
      Bs[kk][j] = w[(size_t)(k0 + kk) * 512 + n0 + j];
    }
    __syncthreads();
#pragma unroll
    for (int kk = 0; kk < 16; ++kk) {
      float av[8], bv[8];
      *(float4*)&av[0] = *(const float4*)&As[kk][ty * 8];
      *(float4*)&av[4] = *(const float4*)&As[kk][ty * 8 + 4];
      *(float4*)&bv[0] = *(const float4*)&Bs[kk][tx * 8];
      *(float4*)&bv[4] = *(const float4*)&Bs[kk][tx * 8 + 4];
#pragma unroll
      for (int i2 = 0; i2 < 8; ++i2)
#pragma unroll
        for (int j2 = 0; j2 < 8; ++j2)
          acc[i2][j2] += av[i2] * bv[j2];
    }
    __syncthreads();
  }

  float4 wb0 = *(const float4*)&wb[n0 + tx * 8];
  float4 wb1 = *(const float4*)&wb[n0 + tx * 8 + 4];
#pragma unroll
  for (int i = 0; i < 8; ++i) {
    int row = r0 + ty * 8 + i;
    float4 o0 = make_float4(acc[i][0] + wb0.x, acc[i][1] + wb0.y,
                            acc[i][2] + wb0.z, acc[i][3] + wb0.w);
    float4 o1 = make_float4(acc[i][4] + wb1.x, acc[i][5] + wb1.y,
                            acc[i][6] + wb1.z, acc[i][7] + wb1.w);
    float4* p = (float4*)&outp[(size_t)row * 512 + n0 + tx * 8];
    p[0] = o0; p[1] = o1;
  }
}

// ---------------------------------------------------------------------------
// LN2 stats: one wave per row over 512 channels of y (row-major)
__global__ __launch_bounds__(256) void ln2_stats(const float* __restrict__ y,
                                                 float* __restrict__ mu,
                                                 float* __restrict__ rs) {
  int wv = threadIdx.x >> 6, lane = threadIdx.x & 63;
  int row = blockIdx.x * 4 + wv;
  const float4* yp = (const float4*)(y + (size_t)row * 512);
  float s = 0.f, s2 = 0.f;
#pragma unroll
  for (int i = 0; i < 2; ++i) {
    float4 v = yp[lane + i * 64];
    s += v.x + v.y + v.z + v.w;
    s2 += v.x * v.x + v.y * v.y + v.z * v.z + v.w * v.w;
  }
#pragma unroll
  for (int o = 32; o; o >>= 1) { s += __shfl_down(s, o); s2 += __shfl_down(s2, o); }
  if (lane == 0) {
    float m = s * (1.0f / 512.0f);
    float var = s2 * (1.0f / 512.0f) - m * m;
    mu[row] = m;
    rs[row] = rsqrtf(var + 1e-5f);
  }
}

// ---------------------------------------------------------------------------
// MLP1: hid(chunk,1024) = gelu( LN2(y)(chunk,512) @ w1(512,1024) + b1 )
__global__ __launch_bounds__(256) void mlp1_gemm(const float* __restrict__ y,
    const float* __restrict__ mu, const float* __restrict__ rs,
    const float* __restrict__ g, const float* __restrict__ be,
    const float* __restrict__ w1, const float* __restrict__ b1,
    float* __restrict__ hid, int row_off) {
  __shared__ float As[16][128];
  __shared__ float Bs[16][128];
  __shared__ float gL[D2], beL[D2], muL[128], rsL[128];
  int tid = threadIdx.x;
  int r0l = blockIdx.x * 128;
  int r0g = row_off + r0l;
  int n0 = blockIdx.y * 128;
  gL[tid] = g[tid]; gL[tid + 256] = g[tid + 256];
  beL[tid] = be[tid]; beL[tid + 256] = be[tid + 256];
  if (tid < 128) { muL[tid] = mu[r0g + tid]; rsL[tid] = rs[r0g + tid]; }
  __syncthreads();

  float acc[8][8] = {};
  int tx = tid & 15, ty = tid >> 4;

  for (int k0 = 0; k0 < D2; k0 += 16) {
#pragma unroll
    for (int i = 0; i < 2; ++i) {
      int e = tid + i * 256;
      int m = e >> 2, qd = e & 3;
      float4 vv = *(const float4*)&y[(size_t)(r0g + m) * 512 + k0 + qd * 4];
      int c0 = k0 + qd * 4;
      float mm = muL[m], rr = rsL[m];
      As[qd * 4 + 0][m] = (vv.x - mm) * rr * gL[c0 + 0] + beL[c0 + 0];
      As[qd * 4 + 1][m] = (vv.y - mm) * rr * gL[c0 + 1] + beL[c0 + 1];
      As[qd * 4 + 2][m] = (vv.z - mm) * rr * gL[c0 + 2] + beL[c0 + 2];
      As[qd * 4 + 3][m] = (vv.w - mm) * rr * gL[c0 + 3] + beL[c0 + 3];
    }
#pragma unroll
    for (int i = 0; i < 8; ++i) {
      int e = tid + i * 256;
      int j = e & 127, kk = e >> 7;
      Bs[kk][j] = w1[(size_t)(k0 + kk) * 1024 + n0 + j];
    }
    __syncthreads();
#pragma unroll
    for (int kk = 0; kk < 16; ++kk) {
      float av[8], bv[8];
      *(float4*)&av[0] = *(const float4*)&As[kk][ty * 8];
      *(float4*)&av[4] = *(const float4*)&As[kk][ty * 8 + 4];
      *(float4*)&bv[0] = *(const float4*)&Bs[kk][tx * 8];
      *(float4*)&bv[4] = *(const float4*)&Bs[kk][tx * 8 + 4];
#pragma unroll
      for (int i2 = 0; i2 < 8; ++i2)
#pragma unroll
        for (int j2 = 0; j2 < 8; ++j2)
          acc[i2][j2] += av[i2] * bv[j2];
    }
    __syncthreads();
  }

  float4 bb0 = *(const float4*)&b1[n0 + tx * 8];
  float4 bb1 = *(const float4*)&b1[n0 + tx * 8 + 4];
  float bb[8] = {bb0.x, bb0.y, bb0.z, bb0.w, bb1.x, bb1.y, bb1.z, bb1.w};
#pragma unroll
  for (int i = 0; i < 8; ++i) {
    float o[8];
#pragma unroll
    for (int j = 0; j < 8; ++j) {
      float t = acc[i][j] + bb[j];
      o[j] = 0.5f * t * (1.0f + erff(t * 0.70710678118654752f));
    }
    float4* p = (float4*)&hid[(size_t)(r0l + ty * 8 + i) * 1024 + n0 + tx * 8];
    p[0] = make_float4(o[0], o[1], o[2], o[3]);
    p[1] = make_float4(o[4], o[5], o[6], o[7]);
  }
}

// ---------------------------------------------------------------------------
// MLP2 + residual + transpose: d_out[b][c][l] = y[row][c] + hid@w2 + b2
__global__ __launch_bounds__(256) void mlp2_gemm(const float* __restrict__ hid,
    const float* __restrict__ w2, const float* __restrict__ b2,
    const float* __restrict__ y, float* __restrict__ outp, int row_off) {
  __shared__ float As[16][128];
  __shared__ float Bs[16][64];
  __shared__ float tT[128][66];
  int tid = threadIdx.x;
  int r0l = blockIdx.x * 128;
  int n0 = blockIdx.y * 64;
  float acc[8][4] = {};
  int tx = tid & 15, ty = tid >> 4;

  for (int k0 = 0; k0 < HID; k0 += 16) {
#pragma unroll
    for (int i = 0; i < 2; ++i) {
      int e = tid + i * 256;
      int m = e >> 2, qd = e & 3;
      float4 vv = *(const float4*)&hid[(size_t)(r0l + m) * 1024 + k0 + qd * 4];
      As[qd * 4 + 0][m] = vv.x; As[qd * 4 + 1][m] = vv.y;
      As[qd * 4 + 2][m] = vv.z; As[qd * 4 + 3][m] = vv.w;
    }
#pragma unroll
    for (int i = 0; i < 4; ++i) {
      int e = tid + i * 256;
      int j = e & 63, kk = e >> 6;
      Bs[kk][j] = w2[(size_t)(k0 + kk) * 512 + n0 + j];
    }
    __syncthreads();
#pragma unroll
    for (int kk = 0; kk < 16; ++kk) {
      float av[8], bv[4];
      *(float4*)&av[0] = *(const float4*)&As[kk][ty * 8];
      *(float4*)&av[4] = *(const float4*)&As[kk][ty * 8 + 4];
      *(float4*)&bv[0] = *(const float4*)&Bs[kk][tx * 4];
#pragma unroll
      for (int i2 = 0; i2 < 8; ++i2)
#pragma unroll
        for (int j2 = 0; j2 < 4; ++j2)
          acc[i2][j2] += av[i2] * bv[j2];
    }
    __syncthreads();
  }

  float4 bb = *(const float4*)&b2[n0 + tx * 4];
#pragma unroll
  for (int i = 0; i < 8; ++i) {
    int grow = row_off + r0l + ty * 8 + i;
    float4 yv = *(const float4*)&y[(size_t)grow * 512 + n0 + tx * 4];
    tT[ty * 8 + i][tx * 4 + 0] = acc[i][0] + bb.x + yv.x;
    tT[ty * 8 + i][tx * 4 + 1] = acc[i][1] + bb.y + yv.y;
    tT[ty * 8 + i][tx * 4 + 2] = acc[i][2] + bb.z + yv.z;
    tT[ty * 8 + i][tx * 4 + 3] = acc[i][3] + bb.w + yv.w;
  }
  __syncthreads();
#pragma unroll
  for (int i = 0; i < 32; ++i) {
    int e = tid + i * 256;
    int m = e & 127, j = e >> 7;
    int grow = row_off + r0l + m;
    int b = grow / L_;
    int l = grow - b * L_;
    outp[(size_t)b * (D2 * L_) + (size_t)(n0 + j) * L_ + l] = tT[m][j];
  }
}

// ---------------------------------------------------------------------------
extern "C" void kernel_launch(void* const* d_in, const int* in_sizes, int n_in,
                              void* d_out, int out_size, void* d_ws, size_t ws_size,
                              hipStream_t stream) {
  const float* x      = (const float*)d_in[0];
  const float* qkv_w  = (const float*)d_in[1];
  const float* qkv_b  = (const float*)d_in[2];
  const float* rel    = (const float*)d_in[3];
  const float* proj_w = (const float*)d_in[4];
  const float* proj_b = (const float*)d_in[5];
  const float* w1     = (const float*)d_in[6];
  const float* b1     = (const float*)d_in[7];
  const float* w2     = (const float*)d_in[8];
  const float* b2     = (const float*)d_in[9];
  const float* g1     = (const float*)d_in[10];
  const float* be1    = (const float*)d_in[11];
  const float* g2     = (const float*)d_in[12];
  const float* be2    = (const float*)d_in[13];
  float* out = (float*)d_out;

  // ws layout (floats):
  //  [0]            mu1   ROWS
  //  [ROWS]         rs1   ROWS
  //  [2*ROWS]       mu2   ROWS
  //  [3*ROWS]       rs2   ROWS
  //  [4*ROWS]       qkv   ROWS*768   (later reused as y: ROWS*512)
  //  [4*ROWS+768R]  attn_out ROWS*256 (later reused as mlp hidden chunk 25600*1024)
  float* wsf = (float*)d_ws;
  float* mu1 = wsf;
  float* rs1 = mu1 + ROWS;
  float* mu2 = rs1 + ROWS;
  float* rs2 = mu2 + ROWS;
  float* qkv = rs2 + ROWS;
  float* y   = qkv;                       // overlays qkv (qkv dead after attention)
  float* att = qkv + (size_t)ROWS * 768;  // attn_out
  float* hid = att;                       // overlays attn_out (dead after proj)

  hipLaunchKernelGGL(ln1_stats, dim3(ROWS / 256), dim3(256), 0, stream, x, mu1, rs1);
  hipLaunchKernelGGL(qkv_gemm, dim3(ROWS / 128, 6), dim3(256), 0, stream,
                     x, mu1, rs1, g1, be1, qkv_w, qkv_b, qkv);
  hipLaunchKernelGGL(attn_kernel, dim3(B_ * NWIN), dim3(256), 0, stream, qkv, rel, att);
  hipLaunchKernelGGL(proj_gemm, dim3(ROWS / 128, 4), dim3(256), 0, stream,
                     att, proj_w, proj_b, y);
  hipLaunchKernelGGL(ln2_stats, dim3(ROWS / 4), dim3(256), 0, stream, y, mu2, rs2);

  const int CHUNK = ROWS / 4;  // 25600 rows per chunk
  for (int c = 0; c < 4; ++c) {
    int off = c * CHUNK;
    hipLaunchKernelGGL(mlp1_gemm, dim3(CHUNK / 128, 8), dim3(256), 0, stream,
                       y, mu2, rs2, g2, be2, w1, b1, hid, off);
    hipLaunchKernelGGL(mlp2_gemm, dim3(CHUNK / 128, 8), dim3(256), 0, stream,
                       hid, w2, b2, y, out, off);
  }
  (void)in_sizes; (void)n_in; (void)out_size; (void)ws_size;
}

// Round 2
// 1219.607 us; speedup vs baseline: 3.6741x; 3.6741x over previous
//
#include <hip/hip_runtime.h>
#include <math.h>

// Problem constants
#define B_   64
#define C_   256
#define L_   1600          // H*W = 40*40
#define T_   25            // tokens per window (5x5)
#define ROWS (B_*L_)       // 102400
#define QSCALE 0.17677669529663687f   // 1/sqrt(32)

typedef _Float16 f16;
typedef f16 f16x8 __attribute__((ext_vector_type(8)));
typedef f16 f16x4 __attribute__((ext_vector_type(4)));
typedef float f32x4 __attribute__((ext_vector_type(4)));

__device__ __forceinline__ void gload_lds16(const void* g, void* l) {
  __builtin_amdgcn_global_load_lds(
      (const __attribute__((address_space(1))) unsigned int*)g,
      (__attribute__((address_space(3))) unsigned int*)l, 16, 0, 0);
}

// ---------------------------------------------------------------------------
// Weight convert+transpose: out(N,K) fp16 = w(K,N) fp32
__global__ __launch_bounds__(256) void wtrans(const float* __restrict__ w,
                                              f16* __restrict__ o, int K, int N) {
  int idx = blockIdx.x * 256 + threadIdx.x;
  if (idx >= K * N) return;
  int n = idx / K, k = idx - n * K;
  o[idx] = (f16)w[(size_t)k * N + n];
}

// ---------------------------------------------------------------------------
// LN1 stats: per (b,l) row over C=256 channels of x (B,C,L)
__global__ __launch_bounds__(256) void ln1_stats(const float* __restrict__ x,
                                                 float* __restrict__ mu,
                                                 float* __restrict__ rs) {
  int r = blockIdx.x * 256 + threadIdx.x;
  int b = r / L_;
  int l = r - b * L_;
  const float* xp = x + (size_t)b * (C_ * L_) + l;
  float s = 0.f, s2 = 0.f;
#pragma unroll 8
  for (int c = 0; c < C_; ++c) {
    float v = xp[(size_t)c * L_];
    s += v; s2 += v * v;
  }
  float m = s * (1.0f / C_);
  float var = s2 * (1.0f / C_) - m * m;
  mu[r] = m;
  rs[r] = rsqrtf(var + 1e-5f);
}

// LN1 apply + transpose: xs(ROWS,256) fp16 row-major from x(B,C,L)
__global__ __launch_bounds__(256) void ln1_apply(const float* __restrict__ x,
    const float* __restrict__ mu, const float* __restrict__ rs,
    const float* __restrict__ g, const float* __restrict__ be,
    f16* __restrict__ xs) {
  __shared__ float t32[256][65];
  int tid = threadIdx.x;
  int r0 = blockIdx.x * 64;
  int rl = tid & 63;
  int grow = r0 + rl;
  int b = grow / L_;
  int l = grow - b * L_;
  float m = mu[grow], r = rs[grow];
  const float* xb = x + (size_t)b * (C_ * L_) + l;
#pragma unroll
  for (int i = 0; i < 64; ++i) {
    int c = i * 4 + (tid >> 6);
    float v = xb[(size_t)c * L_];
    t32[c][rl] = (v - m) * r * g[c] + be[c];
  }
  __syncthreads();
  for (int i = 0; i < 64; ++i) {
    // row i, col tid
    xs[(size_t)(r0 + i) * 256 + tid] = (f16)t32[tid][i];
  }
}

// ---------------------------------------------------------------------------
// MFMA GEMM: C(M,N) = A(M,K)f16 @ BT(N,K)f16^T ; 128x128 tile, BK=32, 4 waves.
// EPI: 0 = +bias -> f16 out ; 1 = +bias -> f32 out ; 2 = gelu(+bias) -> f16 out
//      3 = +bias +resid -> transposed (B,512,L) f32 out
template<int K, int N, int EPI>
__global__ __launch_bounds__(256) void gemm16(
    const f16* __restrict__ A, const f16* __restrict__ BT,
    const float* __restrict__ bias, float* __restrict__ outF,
    f16* __restrict__ outH, const float* __restrict__ resid, int row_off) {
  __shared__ f16 As[128 * 32];
  __shared__ f16 Bs[128 * 32];
  __shared__ float tT[(EPI == 3) ? 64 * 129 : 1];
  int tid = threadIdx.x;
  int w = tid >> 6, lane = tid & 63;
  int wr = w >> 1, wc = w & 1;
  int r0 = blockIdx.x * 128;
  int n0 = blockIdx.y * 128;

  f32x4 acc[4][4] = {};

  for (int k0 = 0; k0 < K; k0 += 32) {
#pragma unroll
    for (int i = 0; i < 2; ++i) {
      int e = i * 256 + tid;
      int row = e >> 2, t = e & 3;
      int cb = t ^ ((row >> 1) & 3);   // inverse-swizzled source colblock
      gload_lds16(A + (size_t)(r0 + row) * K + k0 + cb * 8,
                  &As[(i * 4 + w) * 512]);
    }
#pragma unroll
    for (int i = 0; i < 2; ++i) {
      int e = i * 256 + tid;
      int row = e >> 2, t = e & 3;
      int cb = t ^ ((row >> 1) & 3);
      gload_lds16(BT + (size_t)(n0 + row) * K + k0 + cb * 8,
                  &Bs[(i * 4 + w) * 512]);
    }
    __syncthreads();

    f16x8 af[4], bf[4];
#pragma unroll
    for (int m = 0; m < 4; ++m) {
      int ar = wr * 64 + m * 16 + (lane & 15);
      int sl = (lane >> 4) ^ ((ar >> 1) & 3);  // swizzled read slot
      af[m] = *(const f16x8*)&As[ar * 32 + sl * 8];
    }
#pragma unroll
    for (int n = 0; n < 4; ++n) {
      int br = wc * 64 + n * 16 + (lane & 15);
      int sl = (lane >> 4) ^ ((br >> 1) & 3);
      bf[n] = *(const f16x8*)&Bs[br * 32 + sl * 8];
    }
#pragma unroll
    for (int m = 0; m < 4; ++m)
#pragma unroll
      for (int n = 0; n < 4; ++n)
        acc[m][n] = __builtin_amdgcn_mfma_f32_16x16x32_f16(af[m], bf[n], acc[m][n], 0, 0, 0);
    __syncthreads();
  }

  if constexpr (EPI != 3) {
#pragma unroll
    for (int m = 0; m < 4; ++m) {
#pragma unroll
      for (int n = 0; n < 4; ++n) {
        int gcol = n0 + wc * 64 + n * 16 + (lane & 15);
        float bb = bias[gcol];
#pragma unroll
        for (int j = 0; j < 4; ++j) {
          int grow = r0 + wr * 64 + m * 16 + ((lane >> 4) << 2) + j;
          float v = acc[m][n][j] + bb;
          if constexpr (EPI == 0) {
            outH[(size_t)grow * N + gcol] = (f16)v;
          } else if constexpr (EPI == 1) {
            outF[(size_t)grow * N + gcol] = v;
          } else {
            float gl = 0.5f * v * (1.0f + erff(v * 0.70710678118654752f));
            outH[(size_t)grow * N + gcol] = (f16)gl;
          }
        }
      }
    }
  } else {
    // residual + transpose to (B,512,L)
    for (int p = 0; p < 2; ++p) {
      if (wr == p) {
#pragma unroll
        for (int m = 0; m < 4; ++m) {
          int lr = m * 16 + ((lane >> 4) << 2);
#pragma unroll
          for (int n = 0; n < 4; ++n) {
            int lc = wc * 64 + n * 16 + (lane & 15);
            int gcol = n0 + lc;
            float bb = bias[gcol];
#pragma unroll
            for (int j = 0; j < 4; ++j) {
              int grow = row_off + r0 + p * 64 + lr + j;
              tT[(lr + j) * 129 + lc] =
                  acc[m][n][j] + bb + resid[(size_t)grow * 512 + gcol];
            }
          }
        }
      }
      __syncthreads();
#pragma unroll
      for (int it = 0; it < 8; ++it) {
        int idx = it * 256 + tid;
        int col = idx >> 4;          // 0..127
        int r4 = idx & 15;           // 0..15 (x4 rows)
        int grow0 = row_off + r0 + p * 64 + r4 * 4;
        int b = grow0 / L_;
        int l = grow0 - b * L_;
        float4 o = make_float4(tT[(p * 0 + r4 * 4 + 0) * 129 + col],
                               tT[(r4 * 4 + 1) * 129 + col],
                               tT[(r4 * 4 + 2) * 129 + col],
                               tT[(r4 * 4 + 3) * 129 + col]);
        *(float4*)&outF[((size_t)b * 512 + n0 + col) * L_ + l] = o;
      }
      __syncthreads();
    }
  }
}

// ---------------------------------------------------------------------------
// Window attention: one block per (b, window); reads qkv f16, writes att f16.
__global__ __launch_bounds__(256) void attn_kernel(const f16* __restrict__ qkv,
                                                   const float* __restrict__ rel,
                                                   f16* __restrict__ outp) {
  __shared__ float qk[T_][776];
  __shared__ float sL[8 * T_ * T_];   // 5000 scores
  int tid = threadIdx.x;
  int bn = blockIdx.x;
  int b = bn >> 6, n = bn & 63;
  int u = n >> 3, v = n & 7;

  for (int e = tid; e < T_ * 768; e += 256) {
    int t = e / 768;
    int col = e - t * 768;
    int which = col >> 8;
    int cm = col & 255;
    int d = cm >> 3, h = cm & 7;
    int i = t / 5, j = t - i * 5;
    int l = (u * 5 + i) * 40 + v * 5 + j;
    float val = (float)qkv[(size_t)(b * L_ + l) * 768 + col];
    if (which == 0) val *= QSCALE;
    qk[t][which * 256 + h * 32 + d] = val;
  }
  __syncthreads();

  for (int e = tid; e < 8 * T_ * T_; e += 256) {
    int h = e / 625;
    int r = e - h * 625;
    int t = r / 25, s = r - t * 25;
    const float* qp = &qk[t][h * 32];
    const float* kp = &qk[s][256 + h * 32];
    float dot = 0.f;
#pragma unroll
    for (int d = 0; d < 32; d += 4) {
      float4 q4 = *(const float4*)(qp + d);
      float4 k4 = *(const float4*)(kp + d);
      dot += q4.x * k4.x + q4.y * k4.y + q4.z * k4.z + q4.w * k4.w;
    }
    int i1 = t / 5, j1 = t - i1 * 5;
    int i2 = s / 5, j2 = s - i2 * 5;
    int ridx = (i1 - i2 + 4) * 9 + (j1 - j2 + 4);
    float bias = rel[ridx * 8 + h];
    int p1 = ((u * 5 + i1) + (v * 5 + j1)) & 1;
    int p2 = ((u * 5 + i2) + (v * 5 + j2)) & 1;
    float mval = (p1 & p2) ? 0.0f : -100.0f;
    sL[e] = dot + bias + mval;
  }
  __syncthreads();

  if (tid < 8 * T_) {
    float* row = &sL[tid * 25];
    float mx = row[0];
#pragma unroll
    for (int s = 1; s < 25; ++s) mx = fmaxf(mx, row[s]);
    float sum = 0.f;
#pragma unroll
    for (int s = 0; s < 25; ++s) { float p = __expf(row[s] - mx); row[s] = p; sum += p; }
    float inv = 1.0f / sum;
#pragma unroll
    for (int s = 0; s < 25; ++s) row[s] *= inv;
  }
  __syncthreads();

  for (int e = tid; e < T_ * 64; e += 256) {
    int t = e >> 6;
    int cq = e & 63;
    int h = cq >> 3;
    int dq = (cq & 7) * 4;
    const float* pr = &sL[(h * 25 + t) * 25];
    float4 acc = make_float4(0.f, 0.f, 0.f, 0.f);
#pragma unroll
    for (int s = 0; s < 25; ++s) {
      float p = pr[s];
      const float4 v4 = *(const float4*)&qk[s][512 + h * 32 + dq];
      acc.x += p * v4.x; acc.y += p * v4.y; acc.z += p * v4.z; acc.w += p * v4.w;
    }
    int i = t / 5, j = t - i * 5;
    int l = (u * 5 + i) * 40 + v * 5 + j;
    f16x4 o;
    o[0] = (f16)acc.x; o[1] = (f16)acc.y; o[2] = (f16)acc.z; o[3] = (f16)acc.w;
    *(f16x4*)&outp[(size_t)(b * L_ + l) * 256 + h * 32 + dq] = o;
  }
}

// ---------------------------------------------------------------------------
// LN2 stats: one wave per row over 512 channels of y (row-major)
__global__ __launch_bounds__(256) void ln2_stats(const float* __restrict__ y,
                                                 float* __restrict__ mu,
                                                 float* __restrict__ rs) {
  int wv = threadIdx.x >> 6, lane = threadIdx.x & 63;
  int row = blockIdx.x * 4 + wv;
  const float4* yp = (const float4*)(y + (size_t)row * 512);
  float s = 0.f, s2 = 0.f;
#pragma unroll
  for (int i = 0; i < 2; ++i) {
    float4 v = yp[lane + i * 64];
    s += v.x + v.y + v.z + v.w;
    s2 += v.x * v.x + v.y * v.y + v.z * v.z + v.w * v.w;
  }
#pragma unroll
  for (int o = 32; o; o >>= 1) { s += __shfl_down(s, o); s2 += __shfl_down(s2, o); }
  if (lane == 0) {
    float m = s * (1.0f / 512.0f);
    float var = s2 * (1.0f / 512.0f) - m * m;
    mu[row] = m;
    rs[row] = rsqrtf(var + 1e-5f);
  }
}

// LN2 apply: yln(ROWS,512) f16 = LN(y)*g+b
__global__ __launch_bounds__(256) void ln2_apply(const float* __restrict__ y,
    const float* __restrict__ mu, const float* __restrict__ rs,
    const float* __restrict__ g, const float* __restrict__ be,
    f16* __restrict__ yln) {
  size_t idx = (size_t)blockIdx.x * 256 + threadIdx.x;
  int row = (int)(idx >> 7);
  int c4 = ((int)idx & 127) * 4;
  float4 v = *(const float4*)&y[(size_t)row * 512 + c4];
  float4 gg = *(const float4*)&g[c4];
  float4 bb = *(const float4*)&be[c4];
  float m = mu[row], r = rs[row];
  f16x4 o;
  o[0] = (f16)((v.x - m) * r * gg.x + bb.x);
  o[1] = (f16)((v.y - m) * r * gg.y + bb.y);
  o[2] = (f16)((v.z - m) * r * gg.z + bb.z);
  o[3] = (f16)((v.w - m) * r * gg.w + bb.w);
  *(f16x4*)&yln[(size_t)row * 512 + c4] = o;
}

// ---------------------------------------------------------------------------
extern "C" void kernel_launch(void* const* d_in, const int* in_sizes, int n_in,
                              void* d_out, int out_size, void* d_ws, size_t ws_size,
                              hipStream_t stream) {
  const float* x      = (const float*)d_in[0];
  const float* qkv_w  = (const float*)d_in[1];
  const float* qkv_b  = (const float*)d_in[2];
  const float* rel    = (const float*)d_in[3];
  const float* proj_w = (const float*)d_in[4];
  const float* proj_b = (const float*)d_in[5];
  const float* w1     = (const float*)d_in[6];
  const float* b1     = (const float*)d_in[7];
  const float* w2     = (const float*)d_in[8];
  const float* b2     = (const float*)d_in[9];
  const float* g1     = (const float*)d_in[10];
  const float* be1    = (const float*)d_in[11];
  const float* g2     = (const float*)d_in[12];
  const float* be2    = (const float*)d_in[13];
  float* out = (float*)d_out;

  // ws layout (bytes):
  //   0        : mu1,rs1,mu2,rs2  (4*ROWS f32 = 1,638,400)
  //   1638400  : fp16 weights qkv_wT(768x256) proj_wT(512x256) w1T(1024x512) w2T(512x1024)
  //   4390912  : P0 (210MB): qkv_h f16 (157MB) then y f32 (210MB)
  //   214106112: P1 (105MB): xs_h(52.4) | att_h(52.4) ; later yln f16 (105MB)
  //   318963712: P2 (52.4MB): hid chunk f16 (25600x1024)
  //   total 371,392,512 B
  char* w8 = (char*)d_ws;
  float* mu1 = (float*)w8;
  float* rs1 = mu1 + ROWS;
  float* mu2 = rs1 + ROWS;
  float* rs2 = mu2 + ROWS;
  f16* qkv_wT  = (f16*)(w8 + 1638400);
  f16* proj_wT = qkv_wT + 768 * 256;
  f16* w1T     = proj_wT + 512 * 256;
  f16* w2T     = w1T + 1024 * 512;
  char* P0 = w8 + 4390912;
  f16*   qkv_h = (f16*)P0;
  float* y     = (float*)P0;
  char* P1 = P0 + (size_t)ROWS * 512 * 4;
  f16* xs_h  = (f16*)P1;
  f16* att_h = (f16*)(P1 + (size_t)ROWS * 256 * 2);
  f16* yln   = (f16*)P1;
  char* P2 = P1 + (size_t)ROWS * 512 * 2;
  f16* hid = (f16*)P2;

  wtrans<<<768, 256, 0, stream>>>(qkv_w, qkv_wT, 256, 768);
  wtrans<<<512, 256, 0, stream>>>(proj_w, proj_wT, 256, 512);
  wtrans<<<2048, 256, 0, stream>>>(w1, w1T, 512, 1024);
  wtrans<<<2048, 256, 0, stream>>>(w2, w2T, 1024, 512);

  ln1_stats<<<ROWS / 256, 256, 0, stream>>>(x, mu1, rs1);
  ln1_apply<<<ROWS / 64, 256, 0, stream>>>(x, mu1, rs1, g1, be1, xs_h);

  gemm16<256, 768, 0><<<dim3(ROWS / 128, 6), 256, 0, stream>>>(
      xs_h, qkv_wT, qkv_b, nullptr, qkv_h, nullptr, 0);

  attn_kernel<<<B_ * 64, 256, 0, stream>>>(qkv_h, rel, att_h);

  gemm16<256, 512, 1><<<dim3(ROWS / 128, 4), 256, 0, stream>>>(
      att_h, proj_wT, proj_b, y, nullptr, nullptr, 0);

  ln2_stats<<<ROWS / 4, 256, 0, stream>>>(y, mu2, rs2);
  ln2_apply<<<ROWS * 512 / 4 / 256, 256, 0, stream>>>(y, mu2, rs2, g2, be2, yln);

  const int CHUNK = ROWS / 4;  // 25600 rows
  for (int c = 0; c < 4; ++c) {
    int off = c * CHUNK;
    gemm16<512, 1024, 2><<<dim3(CHUNK / 128, 8), 256, 0, stream>>>(
        yln + (size_t)off * 512, w1T, b1, nullptr, hid, nullptr, 0);
    gemm16<1024, 512, 3><<<dim3(CHUNK / 128, 4), 256, 0, stream>>>(
        hid, w2T, b2, out, nullptr, y, off);
  }
  (void)in_sizes; (void)n_in; (void)out_size; (void)ws_size;
}

// Round 3
// 919.846 us; speedup vs baseline: 4.8715x; 1.3259x over previous
//
#include <hip/hip_runtime.h>
#include <math.h>

// Problem constants
#define B_   64
#define C_   256
#define L_   1600          // H*W = 40*40
#define T_   25            // tokens per window (5x5)
#define ROWS (B_*L_)       // 102400
#define QSCALE 0.17677669529663687f   // 1/sqrt(32)

typedef _Float16 f16;
typedef f16 f16x8 __attribute__((ext_vector_type(8)));
typedef f16 f16x4 __attribute__((ext_vector_type(4)));
typedef float f32x4 __attribute__((ext_vector_type(4)));

__device__ __forceinline__ void gload_lds16(const void* g, void* l) {
  __builtin_amdgcn_global_load_lds(
      (const __attribute__((address_space(1))) unsigned int*)g,
      (__attribute__((address_space(3))) unsigned int*)l, 16, 0, 0);
}

// ---------------------------------------------------------------------------
// Weight convert+transpose: out(N,K) fp16 = w(K,N) fp32
__global__ __launch_bounds__(256) void wtrans(const float* __restrict__ w,
                                              f16* __restrict__ o, int K, int N) {
  int idx = blockIdx.x * 256 + threadIdx.x;
  if (idx >= K * N) return;
  int n = idx / K, k = idx - n * K;
  o[idx] = (f16)w[(size_t)k * N + n];
}

// ---------------------------------------------------------------------------
// LN1 stats: per (b,l) row over C=256 channels of x (B,C,L)
__global__ __launch_bounds__(256) void ln1_stats(const float* __restrict__ x,
                                                 float* __restrict__ mu,
                                                 float* __restrict__ rs) {
  int r = blockIdx.x * 256 + threadIdx.x;
  int b = r / L_;
  int l = r - b * L_;
  const float* xp = x + (size_t)b * (C_ * L_) + l;
  float s = 0.f, s2 = 0.f;
#pragma unroll 8
  for (int c = 0; c < C_; ++c) {
    float v = xp[(size_t)c * L_];
    s += v; s2 += v * v;
  }
  float m = s * (1.0f / C_);
  float var = s2 * (1.0f / C_) - m * m;
  mu[r] = m;
  rs[r] = rsqrtf(var + 1e-5f);
}

// LN1 apply + transpose: xs(ROWS,256) fp16 row-major from x(B,C,L)
__global__ __launch_bounds__(256) void ln1_apply(const float* __restrict__ x,
    const float* __restrict__ mu, const float* __restrict__ rs,
    const float* __restrict__ g, const float* __restrict__ be,
    f16* __restrict__ xs) {
  __shared__ float t32[256][65];
  int tid = threadIdx.x;
  int r0 = blockIdx.x * 64;
  int rl = tid & 63;
  int grow = r0 + rl;
  int b = grow / L_;
  int l = grow - b * L_;
  float m = mu[grow], r = rs[grow];
  const float* xb = x + (size_t)b * (C_ * L_) + l;
#pragma unroll
  for (int i = 0; i < 64; ++i) {
    int c = i * 4 + (tid >> 6);
    float v = xb[(size_t)c * L_];
    t32[c][rl] = (v - m) * r * g[c] + be[c];
  }
  __syncthreads();
  for (int i = 0; i < 64; ++i) {
    xs[(size_t)(r0 + i) * 256 + tid] = (f16)t32[tid][i];
  }
}

// ---------------------------------------------------------------------------
// MFMA GEMM: C(M,N) = A(M,K)f16 @ BT(N,K)f16^T ; 128x128 tile, BK=32, 4 waves.
// EPI: 0 = +bias -> f16 out ; 1 = +bias -> f32 out ; 2 = gelu(+bias) -> f16 out
//      3 = +bias +resid -> transposed (B,512,L) f32 out
template<int K, int N, int EPI>
__global__ __launch_bounds__(256) void gemm16(
    const f16* __restrict__ A, const f16* __restrict__ BT,
    const float* __restrict__ bias, float* __restrict__ outF,
    f16* __restrict__ outH, const float* __restrict__ resid, int row_off) {
  __shared__ f16 As[128 * 32];
  __shared__ f16 Bs[128 * 32];
  __shared__ float tT[(EPI == 3) ? 64 * 129 : 1];
  int tid = threadIdx.x;
  int w = tid >> 6, lane = tid & 63;
  int wr = w >> 1, wc = w & 1;
  int r0 = blockIdx.x * 128;
  int n0 = blockIdx.y * 128;

  f32x4 acc[4][4] = {};

  for (int k0 = 0; k0 < K; k0 += 32) {
#pragma unroll
    for (int i = 0; i < 2; ++i) {
      int e = i * 256 + tid;
      int row = e >> 2, t = e & 3;
      int cb = t ^ ((row >> 1) & 3);   // inverse-swizzled source colblock
      gload_lds16(A + (size_t)(r0 + row) * K + k0 + cb * 8,
                  &As[(i * 4 + w) * 512]);
    }
#pragma unroll
    for (int i = 0; i < 2; ++i) {
      int e = i * 256 + tid;
      int row = e >> 2, t = e & 3;
      int cb = t ^ ((row >> 1) & 3);
      gload_lds16(BT + (size_t)(n0 + row) * K + k0 + cb * 8,
                  &Bs[(i * 4 + w) * 512]);
    }
    __syncthreads();

    f16x8 af[4], bf[4];
#pragma unroll
    for (int m = 0; m < 4; ++m) {
      int ar = wr * 64 + m * 16 + (lane & 15);
      int sl = (lane >> 4) ^ ((ar >> 1) & 3);  // swizzled read slot
      af[m] = *(const f16x8*)&As[ar * 32 + sl * 8];
    }
#pragma unroll
    for (int n = 0; n < 4; ++n) {
      int br = wc * 64 + n * 16 + (lane & 15);
      int sl = (lane >> 4) ^ ((br >> 1) & 3);
      bf[n] = *(const f16x8*)&Bs[br * 32 + sl * 8];
    }
#pragma unroll
    for (int m = 0; m < 4; ++m)
#pragma unroll
      for (int n = 0; n < 4; ++n)
        acc[m][n] = __builtin_amdgcn_mfma_f32_16x16x32_f16(af[m], bf[n], acc[m][n], 0, 0, 0);
    __syncthreads();
  }

  if constexpr (EPI != 3) {
#pragma unroll
    for (int m = 0; m < 4; ++m) {
#pragma unroll
      for (int n = 0; n < 4; ++n) {
        int gcol = n0 + wc * 64 + n * 16 + (lane & 15);
        float bb = bias[gcol];
#pragma unroll
        for (int j = 0; j < 4; ++j) {
          int grow = r0 + wr * 64 + m * 16 + ((lane >> 4) << 2) + j;
          float v = acc[m][n][j] + bb;
          if constexpr (EPI == 0) {
            outH[(size_t)grow * N + gcol] = (f16)v;
          } else if constexpr (EPI == 1) {
            outF[(size_t)grow * N + gcol] = v;
          } else {
            float gl = 0.5f * v * (1.0f + erff(v * 0.70710678118654752f));
            outH[(size_t)grow * N + gcol] = (f16)gl;
          }
        }
      }
    }
  } else {
    // residual + transpose to (B,512,L)
    for (int p = 0; p < 2; ++p) {
      if (wr == p) {
#pragma unroll
        for (int m = 0; m < 4; ++m) {
          int lr = m * 16 + ((lane >> 4) << 2);
#pragma unroll
          for (int n = 0; n < 4; ++n) {
            int lc = wc * 64 + n * 16 + (lane & 15);
            int gcol = n0 + lc;
            float bb = bias[gcol];
#pragma unroll
            for (int j = 0; j < 4; ++j) {
              int grow = row_off + r0 + p * 64 + lr + j;
              tT[(lr + j) * 129 + lc] =
                  acc[m][n][j] + bb + resid[(size_t)grow * 512 + gcol];
            }
          }
        }
      }
      __syncthreads();
#pragma unroll
      for (int it = 0; it < 8; ++it) {
        int idx = it * 256 + tid;
        int col = idx >> 4;          // 0..127
        int r4 = idx & 15;           // 0..15 (x4 rows)
        int grow0 = row_off + r0 + p * 64 + r4 * 4;
        int b = grow0 / L_;
        int l = grow0 - b * L_;
        float4 o = make_float4(tT[(r4 * 4 + 0) * 129 + col],
                               tT[(r4 * 4 + 1) * 129 + col],
                               tT[(r4 * 4 + 2) * 129 + col],
                               tT[(r4 * 4 + 3) * 129 + col]);
        *(float4*)&outF[((size_t)b * 512 + n0 + col) * L_ + l] = o;
      }
      __syncthreads();
    }
  }
}

// ---------------------------------------------------------------------------
// Window attention v2: one block per (b, window). fp16 LDS (50 KB -> 3 blk/CU),
// row-mapped fused score+softmax (K-row reads broadcast), fp16 P.
#define PST 776   // f16 elems per qk LDS row (1552 B, 16B-aligned, stride%128B=16B*... spreads banks)
__global__ __launch_bounds__(256) void attn_kernel(const f16* __restrict__ qkv,
                                                   const float* __restrict__ rel,
                                                   f16* __restrict__ outp) {
  __shared__ f16 qk[T_][PST];        // 25 x 776 f16 = 38800 B  (cols: which*256 + h*32 + d)
  __shared__ f16 pL[8][T_][28];      // 11200 B
  int tid = threadIdx.x;
  int bn = blockIdx.x;
  int b = bn >> 6, n = bn & 63;
  int u = n >> 3, v = n & 7;

  // ---- stage: 25 rows x 96 granules of f16x8; permute d*8+h -> h*32+d
  for (int e = tid; e < T_ * 96; e += 256) {
    int t = e / 96;
    int g = e - t * 96;
    int i = t / 5, j = t - i * 5;
    int l = (u * 5 + i) * 40 + v * 5 + j;
    f16x8 val = *(const f16x8*)&qkv[(size_t)(b * L_ + l) * 768 + g * 8];
    int which = g >> 5;         // 0=q,1=k,2=v
    int d = g & 31;
    if (which == 0) {
#pragma unroll
      for (int h = 0; h < 8; ++h) val[h] = (f16)((float)val[h] * QSCALE);
    }
    int base = which * 256 + d;
#pragma unroll
    for (int h = 0; h < 8; ++h)
      qk[t][base + h * 32] = val[h];
  }
  __syncthreads();

  // ---- fused scores + softmax: thread (h,t) owns one row
  {
    int h = tid >> 5, t = tid & 31;
    if (t < T_) {
      int i1 = t / 5, j1 = t - i1 * 5;
      int par1 = (u + v + i1 + j1) & 1;
      const f16* qp = &qk[t][h * 32];
      f16x8 q0 = *(const f16x8*)(qp + 0);
      f16x8 q1 = *(const f16x8*)(qp + 8);
      f16x8 q2 = *(const f16x8*)(qp + 16);
      f16x8 q3 = *(const f16x8*)(qp + 24);
      float sc[T_];
      float mx = -1e30f;
#pragma unroll
      for (int s = 0; s < T_; ++s) {
        int i2 = s / 5, j2 = s - i2 * 5;
        const f16* kp = &qk[s][256 + h * 32];
        f16x8 k0 = *(const f16x8*)(kp + 0);
        f16x8 k1 = *(const f16x8*)(kp + 8);
        f16x8 k2 = *(const f16x8*)(kp + 16);
        f16x8 k3 = *(const f16x8*)(kp + 24);
        float dot = 0.f;
#pragma unroll
        for (int z = 0; z < 8; ++z) {
          dot += (float)q0[z] * (float)k0[z];
          dot += (float)q1[z] * (float)k1[z];
          dot += (float)q2[z] * (float)k2[z];
          dot += (float)q3[z] * (float)k3[z];
        }
        float bias = rel[((i1 - i2 + 4) * 9 + (j1 - j2 + 4)) * 8 + h];
        int par2 = (u + v + i2 + j2) & 1;
        float scv = dot + bias + ((par1 & par2) ? 0.0f : -100.0f);
        sc[s] = scv;
        mx = fmaxf(mx, scv);
      }
      float sum = 0.f;
#pragma unroll
      for (int s = 0; s < T_; ++s) {
        float p = __expf(sc[s] - mx);
        sc[s] = p;
        sum += p;
      }
      float inv = 1.0f / sum;
#pragma unroll
      for (int s = 0; s < T_; ++s)
        pL[h][t][s] = (f16)(sc[s] * inv);
    }
  }
  __syncthreads();

  // ---- PV: e over 25 tokens x 64 (h,d4) quads ; V reads contiguous, P broadcast
  for (int e = tid; e < T_ * 64; e += 256) {
    int t = e >> 6;
    int cq = e & 63;
    int h = cq >> 3;
    int dq = (cq & 7) * 4;
    float4 acc = make_float4(0.f, 0.f, 0.f, 0.f);
#pragma unroll
    for (int s = 0; s < T_; ++s) {
      float p = (float)pL[h][t][s];
      f16x4 v4 = *(const f16x4*)&qk[s][512 + h * 32 + dq];
      acc.x += p * (float)v4[0];
      acc.y += p * (float)v4[1];
      acc.z += p * (float)v4[2];
      acc.w += p * (float)v4[3];
    }
    int i = t / 5, j = t - i * 5;
    int l = (u * 5 + i) * 40 + v * 5 + j;
    f16x4 o;
    o[0] = (f16)acc.x; o[1] = (f16)acc.y; o[2] = (f16)acc.z; o[3] = (f16)acc.w;
    *(f16x4*)&outp[(size_t)(b * L_ + l) * 256 + h * 32 + dq] = o;
  }
}

// ---------------------------------------------------------------------------
// LN2 stats: one wave per row over 512 channels of y (row-major)
__global__ __launch_bounds__(256) void ln2_stats(const float* __restrict__ y,
                                                 float* __restrict__ mu,
                                                 float* __restrict__ rs) {
  int wv = threadIdx.x >> 6, lane = threadIdx.x & 63;
  int row = blockIdx.x * 4 + wv;
  const float4* yp = (const float4*)(y + (size_t)row * 512);
  float s = 0.f, s2 = 0.f;
#pragma unroll
  for (int i = 0; i < 2; ++i) {
    float4 v = yp[lane + i * 64];
    s += v.x + v.y + v.z + v.w;
    s2 += v.x * v.x + v.y * v.y + v.z * v.z + v.w * v.w;
  }
#pragma unroll
  for (int o = 32; o; o >>= 1) { s += __shfl_down(s, o); s2 += __shfl_down(s2, o); }
  if (lane == 0) {
    float m = s * (1.0f / 512.0f);
    float var = s2 * (1.0f / 512.0f) - m * m;
    mu[row] = m;
    rs[row] = rsqrtf(var + 1e-5f);
  }
}

// LN2 apply: yln(ROWS,512) f16 = LN(y)*g+b
__global__ __launch_bounds__(256) void ln2_apply(const float* __restrict__ y,
    const float* __restrict__ mu, const float* __restrict__ rs,
    const float* __restrict__ g, const float* __restrict__ be,
    f16* __restrict__ yln) {
  size_t idx = (size_t)blockIdx.x * 256 + threadIdx.x;
  int row = (int)(idx >> 7);
  int c4 = ((int)idx & 127) * 4;
  float4 v = *(const float4*)&y[(size_t)row * 512 + c4];
  float4 gg = *(const float4*)&g[c4];
  float4 bb = *(const float4*)&be[c4];
  float m = mu[row], r = rs[row];
  f16x4 o;
  o[0] = (f16)((v.x - m) * r * gg.x + bb.x);
  o[1] = (f16)((v.y - m) * r * gg.y + bb.y);
  o[2] = (f16)((v.z - m) * r * gg.z + bb.z);
  o[3] = (f16)((v.w - m) * r * gg.w + bb.w);
  *(f16x4*)&yln[(size_t)row * 512 + c4] = o;
}

// ---------------------------------------------------------------------------
extern "C" void kernel_launch(void* const* d_in, const int* in_sizes, int n_in,
                              void* d_out, int out_size, void* d_ws, size_t ws_size,
                              hipStream_t stream) {
  const float* x      = (const float*)d_in[0];
  const float* qkv_w  = (const float*)d_in[1];
  const float* qkv_b  = (const float*)d_in[2];
  const float* rel    = (const float*)d_in[3];
  const float* proj_w = (const float*)d_in[4];
  const float* proj_b = (const float*)d_in[5];
  const float* w1     = (const float*)d_in[6];
  const float* b1     = (const float*)d_in[7];
  const float* w2     = (const float*)d_in[8];
  const float* b2     = (const float*)d_in[9];
  const float* g1     = (const float*)d_in[10];
  const float* be1    = (const float*)d_in[11];
  const float* g2     = (const float*)d_in[12];
  const float* be2    = (const float*)d_in[13];
  float* out = (float*)d_out;

  // ws layout (bytes): see round-2 comment; unchanged.
  char* w8 = (char*)d_ws;
  float* mu1 = (float*)w8;
  float* rs1 = mu1 + ROWS;
  float* mu2 = rs1 + ROWS;
  float* rs2 = mu2 + ROWS;
  f16* qkv_wT  = (f16*)(w8 + 1638400);
  f16* proj_wT = qkv_wT + 768 * 256;
  f16* w1T     = proj_wT + 512 * 256;
  f16* w2T     = w1T + 1024 * 512;
  char* P0 = w8 + 4390912;
  f16*   qkv_h = (f16*)P0;
  float* y     = (float*)P0;
  char* P1 = P0 + (size_t)ROWS * 512 * 4;
  f16* xs_h  = (f16*)P1;
  f16* att_h = (f16*)(P1 + (size_t)ROWS * 256 * 2);
  f16* yln   = (f16*)P1;
  char* P2 = P1 + (size_t)ROWS * 512 * 2;
  f16* hid = (f16*)P2;

  wtrans<<<768, 256, 0, stream>>>(qkv_w, qkv_wT, 256, 768);
  wtrans<<<512, 256, 0, stream>>>(proj_w, proj_wT, 256, 512);
  wtrans<<<2048, 256, 0, stream>>>(w1, w1T, 512, 1024);
  wtrans<<<2048, 256, 0, stream>>>(w2, w2T, 1024, 512);

  ln1_stats<<<ROWS / 256, 256, 0, stream>>>(x, mu1, rs1);
  ln1_apply<<<ROWS / 64, 256, 0, stream>>>(x, mu1, rs1, g1, be1, xs_h);

  gemm16<256, 768, 0><<<dim3(ROWS / 128, 6), 256, 0, stream>>>(
      xs_h, qkv_wT, qkv_b, nullptr, qkv_h, nullptr, 0);

  attn_kernel<<<B_ * 64, 256, 0, stream>>>(qkv_h, rel, att_h);

  gemm16<256, 512, 1><<<dim3(ROWS / 128, 4), 256, 0, stream>>>(
      att_h, proj_wT, proj_b, y, nullptr, nullptr, 0);

  ln2_stats<<<ROWS / 4, 256, 0, stream>>>(y, mu2, rs2);
  ln2_apply<<<ROWS * 512 / 4 / 256, 256, 0, stream>>>(y, mu2, rs2, g2, be2, yln);

  const int CHUNK = ROWS / 4;  // 25600 rows
  for (int c = 0; c < 4; ++c) {
    int off = c * CHUNK;
    gemm16<512, 1024, 2><<<dim3(CHUNK / 128, 8), 256, 0, stream>>>(
        yln + (size_t)off * 512, w1T, b1, nullptr, hid, nullptr, 0);
    gemm16<1024, 512, 3><<<dim3(CHUNK / 128, 4), 256, 0, stream>>>(
        hid, w2T, b2, out, nullptr, y, off);
  }
  (void)in_sizes; (void)n_in; (void)out_size; (void)ws_size;
}